// Round 1
// baseline (211.522 us; speedup 1.0000x reference)
//
#include <hip/hip_runtime.h>

typedef unsigned short ushort_t;
typedef __attribute__((ext_vector_type(8))) short bf16x8;
typedef __attribute__((ext_vector_type(4))) float f32x4;
typedef __attribute__((ext_vector_type(8))) unsigned short u16x8;

#define AS1 __attribute__((address_space(1)))
#define AS3 __attribute__((address_space(3)))

// RNE float -> bf16
static __device__ __forceinline__ unsigned short f2bf(float f) {
    unsigned u = __float_as_uint(f);
    u += 0x7fffu + ((u >> 16) & 1u);
    return (unsigned short)(u >> 16);
}

// ---------------------------------------------------------------------------
// K1: per-row sum-of-squares + fp32 -> bf16 conversion. One wave per row
// (C = 512 floats = 64 lanes x 8). Block = 4 waves = 4 rows.
// ---------------------------------------------------------------------------
__global__ __launch_bounds__(256) void prep_kernel(
    const float* __restrict__ src, ushort_t* __restrict__ dst,
    float* __restrict__ sq)
{
    const int row  = blockIdx.x * 4 + (threadIdx.x >> 6);
    const int lane = threadIdx.x & 63;
    const float4* s = (const float4*)(src + (size_t)row * 512);
    float4 v0 = s[lane * 2 + 0];
    float4 v1 = s[lane * 2 + 1];
    float ss = v0.x*v0.x + v0.y*v0.y + v0.z*v0.z + v0.w*v0.w
             + v1.x*v1.x + v1.y*v1.y + v1.z*v1.z + v1.w*v1.w;
    #pragma unroll
    for (int m = 32; m >= 1; m >>= 1) ss += __shfl_xor(ss, m);
    if (lane == 0) sq[row] = ss;
    u16x8 o;
    o[0]=f2bf(v0.x); o[1]=f2bf(v0.y); o[2]=f2bf(v0.z); o[3]=f2bf(v0.w);
    o[4]=f2bf(v1.x); o[5]=f2bf(v1.y); o[6]=f2bf(v1.z); o[7]=f2bf(v1.w);
    *(u16x8*)(dst + (size_t)row * 512 + lane * 8) = o;
}

// ---------------------------------------------------------------------------
// K2: cross[p][n] GEMM (M=512, N=65536, K=512), 128x128 tile, BK=64,
// 4 waves in 2x2, each wave 64x64 via 4x4 frags of mfma_f32_16x16x32_bf16.
// global_load_lds width-16 staging; XOR chunk swizzle (rule 21: linear LDS
// dest + inverse-swizzled global source + swizzled ds_read address).
// Epilogue: inv-distance -> inv_out (P x N), deterministic partial row sums.
// ---------------------------------------------------------------------------
__global__ __launch_bounds__(256) void gemm_kernel(
    const ushort_t* __restrict__ pb, const ushort_t* __restrict__ xb,
    const float* __restrict__ p_sq, const float* __restrict__ x_sq,
    float* __restrict__ inv_out, float* __restrict__ partial, int Nn)
{
    __shared__ ushort_t As[128 * 64];   // [row 128][k 64] bf16, chunk-swizzled
    __shared__ ushort_t Bs[128 * 64];
    const int tid  = threadIdx.x;
    const int lane = tid & 63, wid = tid >> 6;
    const int wm = wid >> 1, wn = wid & 1;
    const int l15 = lane & 15, l4 = lane >> 4;
    const int m0 = blockIdx.x * 128;
    const int n0 = blockIdx.y * 128;

    f32x4 acc[4][4] = {};

    for (int kt = 0; kt < 512; kt += 64) {
        #pragma unroll
        for (int it = 0; it < 4; ++it) {
            const int cbase = it * 256 + wid * 64;      // wave-uniform chunk base
            const int cid   = cbase + lane;             // this lane's 16B chunk
            const int r     = cid >> 3;                 // tile row
            const int cl    = (cid & 7) ^ (r & 7);      // logical k-chunk (inverse swz)
            const ushort_t* ga = pb + (size_t)(m0 + r) * 512 + kt + cl * 8;
            __builtin_amdgcn_global_load_lds((const AS1 unsigned int*)ga,
                (AS3 unsigned int*)(As + cbase * 8), 16, 0, 0);
            const ushort_t* gb = xb + (size_t)(n0 + r) * 512 + kt + cl * 8;
            __builtin_amdgcn_global_load_lds((const AS1 unsigned int*)gb,
                (AS3 unsigned int*)(Bs + cbase * 8), 16, 0, 0);
        }
        __syncthreads();
        #pragma unroll
        for (int kk = 0; kk < 2; ++kk) {
            bf16x8 a[4], b[4];
            #pragma unroll
            for (int mi = 0; mi < 4; ++mi) {
                const int rr = wm * 64 + mi * 16 + l15;
                const int c  = kk * 4 + l4;
                a[mi] = *(const bf16x8*)&As[(rr * 8 + (c ^ (rr & 7))) * 8];
            }
            #pragma unroll
            for (int ni = 0; ni < 4; ++ni) {
                const int rr = wn * 64 + ni * 16 + l15;
                const int c  = kk * 4 + l4;
                b[ni] = *(const bf16x8*)&Bs[(rr * 8 + (c ^ (rr & 7))) * 8];
            }
            #pragma unroll
            for (int mi = 0; mi < 4; ++mi)
                #pragma unroll
                for (int ni = 0; ni < 4; ++ni)
                    acc[mi][ni] = __builtin_amdgcn_mfma_f32_16x16x32_bf16(
                        a[mi], b[ni], acc[mi][ni], 0, 0, 0);
        }
        __syncthreads();
    }

    // Epilogue: inv = sqrt(512)/sqrt(||p||^2 + ||x||^2 - 2*cross)
    // D frag layout (m89): col = lane&15 (-> n), row = (lane>>4)*4 + j (-> p)
    float psum[4][4] = {};   // [mi][j] partial over this wave's 64 n-cols
    #pragma unroll
    for (int mi = 0; mi < 4; ++mi) {
        const int pbase = m0 + wm * 64 + mi * 16 + l4 * 4;
        #pragma unroll
        for (int ni = 0; ni < 4; ++ni) {
            const int n  = n0 + wn * 64 + ni * 16 + l15;
            const float xs = x_sq[n];
            #pragma unroll
            for (int j = 0; j < 4; ++j) {
                float d2 = p_sq[pbase + j] + xs - 2.0f * acc[mi][ni][j];
                d2 = fmaxf(d2, 1e-20f);
                const float iv = 22.62741699796952f * rsqrtf(d2);
                inv_out[(size_t)(pbase + j) * Nn + n] = iv;
                psum[mi][j] += iv;
            }
        }
    }
    // reduce across the 16 lanes sharing each row (l&15 varies n only)
    #pragma unroll
    for (int mi = 0; mi < 4; ++mi)
        #pragma unroll
        for (int j = 0; j < 4; ++j) {
            float s = psum[mi][j];
            s += __shfl_xor(s, 1); s += __shfl_xor(s, 2);
            s += __shfl_xor(s, 4); s += __shfl_xor(s, 8);
            psum[mi][j] = s;
        }
    float* sp = (float*)As;  // reuse LDS: [128 rows][2 wn]
    if (l15 == 0) {
        #pragma unroll
        for (int mi = 0; mi < 4; ++mi)
            #pragma unroll
            for (int j = 0; j < 4; ++j)
                sp[(wm * 64 + mi * 16 + l4 * 4 + j) * 2 + wn] = psum[mi][j];
    }
    __syncthreads();
    if (tid < 128)
        partial[(size_t)(m0 + tid) * gridDim.y + blockIdx.y] = sp[tid * 2] + sp[tid * 2 + 1];
}

// ---------------------------------------------------------------------------
// K3: sum partials per prototype row -> reciprocal (deterministic tree)
// ---------------------------------------------------------------------------
__global__ __launch_bounds__(256) void rowsum_kernel(
    const float* __restrict__ partial, float* __restrict__ rcp, int nb)
{
    const int p = blockIdx.x;
    const int tid = threadIdx.x;
    float s = 0.0f;
    for (int i = tid; i < nb; i += 256) s += partial[(size_t)p * nb + i];
    #pragma unroll
    for (int m = 32; m >= 1; m >>= 1) s += __shfl_xor(s, m);
    __shared__ float red[4];
    if ((tid & 63) == 0) red[tid >> 6] = s;
    __syncthreads();
    if (tid == 0) rcp[p] = 1.0f / (red[0] + red[1] + red[2] + red[3]);
}

// ---------------------------------------------------------------------------
// K4: weights = inv * rcp (in place, coalesced along n) and
//     x_out[n][c] = weights[c][n] * x[n][c] via 64x64 LDS transpose tile.
// ---------------------------------------------------------------------------
__global__ __launch_bounds__(256) void finalize_kernel(
    const float* __restrict__ x, float* __restrict__ w,
    const float* __restrict__ rcp, float* __restrict__ xout, int Nn)
{
    __shared__ float T[64][65];        // T[n_local][p_local]
    const int tid = threadIdx.x;
    const int tx = tid & 15, ty = tid >> 4;
    const int p0 = blockIdx.x * 64, n0 = blockIdx.y * 64;
    #pragma unroll
    for (int rr = 0; rr < 4; ++rr) {
        const int pl = ty + rr * 16;
        const size_t idx = (size_t)(p0 + pl) * Nn + n0 + tx * 4;
        const float4 iv = *(const float4*)(w + idx);
        const float rc = rcp[p0 + pl];
        float4 wv;
        wv.x = iv.x * rc; wv.y = iv.y * rc; wv.z = iv.z * rc; wv.w = iv.w * rc;
        *(float4*)(w + idx) = wv;
        T[tx * 4 + 0][pl] = wv.x;
        T[tx * 4 + 1][pl] = wv.y;
        T[tx * 4 + 2][pl] = wv.z;
        T[tx * 4 + 3][pl] = wv.w;
    }
    __syncthreads();
    #pragma unroll
    for (int rr = 0; rr < 4; ++rr) {
        const int nl = ty + rr * 16;
        const size_t ix = (size_t)(n0 + nl) * 512 + p0 + tx * 4;
        const float4 xv = *(const float4*)(x + ix);
        float4 ov;
        ov.x = xv.x * T[nl][tx * 4 + 0];
        ov.y = xv.y * T[nl][tx * 4 + 1];
        ov.z = xv.z * T[nl][tx * 4 + 2];
        ov.w = xv.w * T[nl][tx * 4 + 3];
        *(float4*)(xout + ix) = ov;
    }
}

// ---------------------------------------------------------------------------
// Host launch. Scratch strategy: the x_out half of d_out is written only by
// K4, so its 128 MB hosts x-bf16 / proto-bf16 / sq / partials during K1-K3.
// d_ws only holds rcp (2 KB) which must survive into K4.
// ---------------------------------------------------------------------------
extern "C" void kernel_launch(void* const* d_in, const int* in_sizes, int n_in,
                              void* d_out, int out_size, void* d_ws, size_t ws_size,
                              hipStream_t stream)
{
    const float* x     = (const float*)d_in[0];
    const float* proto = (const float*)d_in[1];
    const int C = 512, P = 512;
    const int N = in_sizes[0] / C;            // 65536

    float* out  = (float*)d_out;
    float* xout = out;                        // N*C floats
    float* wout = out + (size_t)N * C;        // P*N floats (inv, then weights)

    char* scr = (char*)d_out;                 // scratch inside x_out region
    ushort_t* xb   = (ushort_t*)scr;                  // N*512 bf16 = 64 MiB
    ushort_t* pbf  = (ushort_t*)(scr + 67108864);     // P*512 bf16 = 512 KiB
    float*    x_sq = (float*)(scr + 67633152);        // N f32
    float*    p_sq = (float*)(scr + 67895296);        // P f32
    float*    part = (float*)(scr + 67897344);        // P * (N/128) f32 = 1 MiB
    float*    rcp  = (float*)d_ws;                    // P f32 (survives into K4)

    prep_kernel<<<N / 4, 256, 0, stream>>>(x, xb, x_sq);
    prep_kernel<<<P / 4, 256, 0, stream>>>(proto, pbf, p_sq);
    gemm_kernel<<<dim3(P / 128, N / 128), 256, 0, stream>>>(pbf, xb, p_sq, x_sq, wout, part, N);
    rowsum_kernel<<<P, 256, 0, stream>>>(part, rcp, N / 128);
    finalize_kernel<<<dim3(P / 64, N / 64), 256, 0, stream>>>(x, wout, rcp, xout, N);
}

// Round 2
// 195.765 us; speedup vs baseline: 1.0805x; 1.0805x over previous
//
#include <hip/hip_runtime.h>

typedef unsigned short ushort_t;
typedef __attribute__((ext_vector_type(8))) short bf16x8;
typedef __attribute__((ext_vector_type(4))) float f32x4;
typedef __attribute__((ext_vector_type(8))) unsigned short u16x8;
typedef __attribute__((ext_vector_type(4))) unsigned short u16x4;

#define AS1 __attribute__((address_space(1)))
#define AS3 __attribute__((address_space(3)))

// RNE float -> bf16
static __device__ __forceinline__ unsigned short f2bf(float f) {
    unsigned u = __float_as_uint(f);
    u += 0x7fffu + ((u >> 16) & 1u);
    return (unsigned short)(u >> 16);
}
static __device__ __forceinline__ float bf2f(unsigned short u) {
    return __uint_as_float(((unsigned)u) << 16);
}

// ---------------------------------------------------------------------------
// K1: per-row sum-of-squares + fp32 -> bf16. One wave per row (C=512).
// ---------------------------------------------------------------------------
__global__ __launch_bounds__(256) void prep_kernel(
    const float* __restrict__ src, ushort_t* __restrict__ dst,
    float* __restrict__ sq)
{
    const int row  = blockIdx.x * 4 + (threadIdx.x >> 6);
    const int lane = threadIdx.x & 63;
    const float4* s = (const float4*)(src + (size_t)row * 512);
    float4 v0 = s[lane * 2 + 0];
    float4 v1 = s[lane * 2 + 1];
    float ss = v0.x*v0.x + v0.y*v0.y + v0.z*v0.z + v0.w*v0.w
             + v1.x*v1.x + v1.y*v1.y + v1.z*v1.z + v1.w*v1.w;
    #pragma unroll
    for (int m = 32; m >= 1; m >>= 1) ss += __shfl_xor(ss, m);
    if (lane == 0) sq[row] = ss;
    u16x8 o;
    o[0]=f2bf(v0.x); o[1]=f2bf(v0.y); o[2]=f2bf(v0.z); o[3]=f2bf(v0.w);
    o[4]=f2bf(v1.x); o[5]=f2bf(v1.y); o[6]=f2bf(v1.z); o[7]=f2bf(v1.w);
    *(u16x8*)(dst + (size_t)row * 512 + lane * 8) = o;
}

// ---------------------------------------------------------------------------
// K2: cross GEMM (M=512 protos, N=65536, K=512), 128x128 tile, BK=64,
// mfma_f32_16x16x32_bf16, global_load_lds w=16, XOR chunk swizzle.
// MODE 0: epilogue computes inv-distances, reduces deterministic partial row
//         sums only (no store of inv).
// MODE 1: epilogue computes w = inv * rcp[p], writes weights AND x_out
//         (x_out tile via in-LDS transpose, x read from bf16 xb).
// MODE 2: like 1 but weights only (safe-scratch fallback path).
// ---------------------------------------------------------------------------
template<int MODE>
__global__ __launch_bounds__(256) void gemm_kernel(
    const ushort_t* __restrict__ pb, const ushort_t* __restrict__ xb,
    const float* __restrict__ p_sq, const float* __restrict__ x_sq,
    const float* __restrict__ rcp,
    float* __restrict__ wout, float* __restrict__ xout,
    float* __restrict__ partial, int Nn)
{
    __shared__ __align__(16) char smem[33280];   // As+Bs (32KB) / Tr[128][65]
    ushort_t* As = (ushort_t*)smem;
    ushort_t* Bs = (ushort_t*)(smem + 16384);

    const int tid  = threadIdx.x;
    const int lane = tid & 63, wid = tid >> 6;
    const int wm = wid >> 1, wn = wid & 1;
    const int l15 = lane & 15, l4 = lane >> 4;
    const int m0 = blockIdx.x * 128;
    const int n0 = blockIdx.y * 128;

    f32x4 acc[4][4] = {};

    for (int kt = 0; kt < 512; kt += 64) {
        #pragma unroll
        for (int it = 0; it < 4; ++it) {
            const int cbase = it * 256 + wid * 64;      // wave-uniform chunk base
            const int cid   = cbase + lane;
            const int r     = cid >> 3;                 // tile row
            const int cl    = (cid & 7) ^ (r & 7);      // inverse-swizzled k-chunk
            const ushort_t* ga = pb + (size_t)(m0 + r) * 512 + kt + cl * 8;
            __builtin_amdgcn_global_load_lds((const AS1 unsigned int*)ga,
                (AS3 unsigned int*)(As + cbase * 8), 16, 0, 0);
            const ushort_t* gb = xb + (size_t)(n0 + r) * 512 + kt + cl * 8;
            __builtin_amdgcn_global_load_lds((const AS1 unsigned int*)gb,
                (AS3 unsigned int*)(Bs + cbase * 8), 16, 0, 0);
        }
        __syncthreads();
        #pragma unroll
        for (int kk = 0; kk < 2; ++kk) {
            bf16x8 a[4], b[4];
            #pragma unroll
            for (int mi = 0; mi < 4; ++mi) {
                const int rr = wm * 64 + mi * 16 + l15;
                const int c  = kk * 4 + l4;
                a[mi] = *(const bf16x8*)&As[(rr * 8 + (c ^ (rr & 7))) * 8];
            }
            #pragma unroll
            for (int ni = 0; ni < 4; ++ni) {
                const int rr = wn * 64 + ni * 16 + l15;
                const int c  = kk * 4 + l4;
                b[ni] = *(const bf16x8*)&Bs[(rr * 8 + (c ^ (rr & 7))) * 8];
            }
            #pragma unroll
            for (int mi = 0; mi < 4; ++mi)
                #pragma unroll
                for (int ni = 0; ni < 4; ++ni)
                    acc[mi][ni] = __builtin_amdgcn_mfma_f32_16x16x32_bf16(
                        a[mi], b[ni], acc[mi][ni], 0, 0, 0);
        }
        __syncthreads();
    }

    // D frag (m89): col = lane&15 (-> n), row = (lane>>4)*4 + j (-> p)
    if (MODE == 0) {
        float psum[4][4] = {};
        #pragma unroll
        for (int mi = 0; mi < 4; ++mi) {
            const int pbase = m0 + wm * 64 + mi * 16 + l4 * 4;
            const f32x4 ps4 = *(const f32x4*)(p_sq + pbase);
            #pragma unroll
            for (int ni = 0; ni < 4; ++ni) {
                const int n = n0 + wn * 64 + ni * 16 + l15;
                const float xs = x_sq[n];
                #pragma unroll
                for (int j = 0; j < 4; ++j) {
                    float d2 = ps4[j] + xs - 2.0f * acc[mi][ni][j];
                    d2 = fmaxf(d2, 1e-20f);
                    psum[mi][j] += 22.62741699796952f * rsqrtf(d2);
                }
            }
        }
        #pragma unroll
        for (int mi = 0; mi < 4; ++mi)
            #pragma unroll
            for (int j = 0; j < 4; ++j) {
                float s = psum[mi][j];
                s += __shfl_xor(s, 1); s += __shfl_xor(s, 2);
                s += __shfl_xor(s, 4); s += __shfl_xor(s, 8);
                psum[mi][j] = s;
            }
        float* sp = (float*)smem;  // [128 rows][2 wn]
        if (l15 == 0) {
            #pragma unroll
            for (int mi = 0; mi < 4; ++mi)
                #pragma unroll
                for (int j = 0; j < 4; ++j)
                    sp[(wm * 64 + mi * 16 + l4 * 4 + j) * 2 + wn] = psum[mi][j];
        }
        __syncthreads();
        if (tid < 128)
            partial[(size_t)(m0 + tid) * gridDim.y + blockIdx.y] =
                sp[tid * 2] + sp[tid * 2 + 1];
    } else {
        // w = inv * rcp[p]; write weights; keep w in acc for the transpose.
        #pragma unroll
        for (int mi = 0; mi < 4; ++mi) {
            const int pbase = m0 + wm * 64 + mi * 16 + l4 * 4;
            const f32x4 ps4 = *(const f32x4*)(p_sq + pbase);
            const f32x4 rc4 = *(const f32x4*)(rcp + pbase);
            #pragma unroll
            for (int ni = 0; ni < 4; ++ni) {
                const int n = n0 + wn * 64 + ni * 16 + l15;
                const float xs = x_sq[n];
                #pragma unroll
                for (int j = 0; j < 4; ++j) {
                    float d2 = ps4[j] + xs - 2.0f * acc[mi][ni][j];
                    d2 = fmaxf(d2, 1e-20f);
                    const float w = 22.62741699796952f * rsqrtf(d2) * rc4[j];
                    acc[mi][ni][j] = w;
                    wout[(size_t)(pbase + j) * Nn + n] = w;
                }
            }
        }
        if (MODE == 1) {
            // x_out[n][c] = w[c][n] * x[n][c] for c in this block's p-range.
            float (*Tr)[65] = (float(*)[65])smem;
            const int tx = tid & 15, ty = tid >> 4;
            #pragma unroll
            for (int h = 0; h < 2; ++h) {
                __syncthreads();
                if (wm == h) {
                    #pragma unroll
                    for (int mi = 0; mi < 4; ++mi)
                        #pragma unroll
                        for (int ni = 0; ni < 4; ++ni)
                            #pragma unroll
                            for (int j = 0; j < 4; ++j)
                                Tr[wn * 64 + ni * 16 + l15][mi * 16 + l4 * 4 + j]
                                    = acc[mi][ni][j];
                }
                __syncthreads();
                #pragma unroll
                for (int rr = 0; rr < 8; ++rr) {
                    const int nl = ty + rr * 16;
                    const size_t gx = (size_t)(n0 + nl) * 512 + m0 + h * 64 + tx * 4;
                    const u16x4 xv = *(const u16x4*)(xb + gx);
                    f32x4 ov;
                    ov[0] = bf2f(xv[0]) * Tr[nl][tx * 4 + 0];
                    ov[1] = bf2f(xv[1]) * Tr[nl][tx * 4 + 1];
                    ov[2] = bf2f(xv[2]) * Tr[nl][tx * 4 + 2];
                    ov[3] = bf2f(xv[3]) * Tr[nl][tx * 4 + 3];
                    *(f32x4*)(xout + gx) = ov;
                }
            }
        }
    }
}

// ---------------------------------------------------------------------------
// K3: sum partials per prototype row -> reciprocal (deterministic tree)
// ---------------------------------------------------------------------------
__global__ __launch_bounds__(256) void rowsum_kernel(
    const float* __restrict__ partial, float* __restrict__ rcp, int nb)
{
    const int p = blockIdx.x;
    const int tid = threadIdx.x;
    float s = 0.0f;
    for (int i = tid; i < nb; i += 256) s += partial[(size_t)p * nb + i];
    #pragma unroll
    for (int m = 32; m >= 1; m >>= 1) s += __shfl_xor(s, m);
    __shared__ float red[4];
    if ((tid & 63) == 0) red[tid >> 6] = s;
    __syncthreads();
    if (tid == 0) rcp[p] = 1.0f / (red[0] + red[1] + red[2] + red[3]);
}

// ---------------------------------------------------------------------------
// K5 (fallback path only): x_out[n][c] = w[c][n] * x[n][c], 64x64 LDS transpose
// ---------------------------------------------------------------------------
__global__ __launch_bounds__(256) void finalize2_kernel(
    const float* __restrict__ x, const float* __restrict__ w,
    float* __restrict__ xout, int Nn)
{
    __shared__ float T[64][65];
    const int tid = threadIdx.x;
    const int tx = tid & 15, ty = tid >> 4;
    const int p0 = blockIdx.x * 64, n0 = blockIdx.y * 64;
    #pragma unroll
    for (int rr = 0; rr < 4; ++rr) {
        const int pl = ty + rr * 16;
        const f32x4 wv = *(const f32x4*)(w + (size_t)(p0 + pl) * Nn + n0 + tx * 4);
        T[tx * 4 + 0][pl] = wv[0];
        T[tx * 4 + 1][pl] = wv[1];
        T[tx * 4 + 2][pl] = wv[2];
        T[tx * 4 + 3][pl] = wv[3];
    }
    __syncthreads();
    #pragma unroll
    for (int rr = 0; rr < 4; ++rr) {
        const int nl = ty + rr * 16;
        const size_t ix = (size_t)(n0 + nl) * 512 + p0 + tx * 4;
        const f32x4 xv = *(const f32x4*)(x + ix);
        f32x4 ov;
        ov[0] = xv[0] * T[nl][tx * 4 + 0];
        ov[1] = xv[1] * T[nl][tx * 4 + 1];
        ov[2] = xv[2] * T[nl][tx * 4 + 2];
        ov[3] = xv[3] * T[nl][tx * 4 + 3];
        *(f32x4*)(xout + ix) = ov;
    }
}

// ---------------------------------------------------------------------------
// Host launch. Two scratch strategies:
//  big d_ws  : scratch in d_ws; pass2 fused (weights + x_out in one kernel).
//  small d_ws: scratch in the x_out half of d_out (only K5 writes that half,
//              last); pass2 writes weights only; K5 reads w + x(f32).
// ---------------------------------------------------------------------------
extern "C" void kernel_launch(void* const* d_in, const int* in_sizes, int n_in,
                              void* d_out, int out_size, void* d_ws, size_t ws_size,
                              hipStream_t stream)
{
    const float* x     = (const float*)d_in[0];
    const float* proto = (const float*)d_in[1];
    const int C = 512, P = 512;
    const int N = in_sizes[0] / C;            // 65536
    const int NB = N / 128;                   // GEMM n-blocks

    float* xout = (float*)d_out;              // N*C floats
    float* wout = xout + (size_t)N * C;       // P*N floats

    const size_t xb_b   = (size_t)N * C * 2;  // 64 MiB
    const size_t pbf_b  = (size_t)P * C * 2;  // 512 KiB
    const size_t need   = xb_b + pbf_b + (size_t)(N + P) * 4
                        + (size_t)P * NB * 4 + (size_t)P * 4;
    const bool big = ws_size >= need;
    char* scr = big ? (char*)d_ws : (char*)d_out;   // small: inside x_out half

    ushort_t* xb   = (ushort_t*)scr;
    ushort_t* pbf  = (ushort_t*)(scr + xb_b);
    float*    x_sq = (float*)(scr + xb_b + pbf_b);
    float*    p_sq = x_sq + N;
    float*    part = p_sq + P;
    float*    rcp  = part + (size_t)P * NB;

    prep_kernel<<<N / 4, 256, 0, stream>>>(x, xb, x_sq);
    prep_kernel<<<P / 4, 256, 0, stream>>>(proto, pbf, p_sq);
    gemm_kernel<0><<<dim3(P / 128, NB), 256, 0, stream>>>(
        pbf, xb, p_sq, x_sq, nullptr, nullptr, nullptr, part, N);
    rowsum_kernel<<<P, 256, 0, stream>>>(part, rcp, NB);
    if (big) {
        gemm_kernel<1><<<dim3(P / 128, NB), 256, 0, stream>>>(
            pbf, xb, p_sq, x_sq, rcp, wout, xout, nullptr, N);
    } else {
        gemm_kernel<2><<<dim3(P / 128, NB), 256, 0, stream>>>(
            pbf, xb, p_sq, x_sq, rcp, wout, nullptr, nullptr, N);
        finalize2_kernel<<<dim3(P / 64, N / 64), 256, 0, stream>>>(
            x, wout, xout, N);
    }
}